// Round 12
// baseline (811.490 us; speedup 1.0000x reference)
//
#include <hip/hip_runtime.h>
#include <hip/hip_bf16.h>
#include <math.h>
#include <stdint.h>

#define N_ATOMS 60000
#define M_NBR   12
#define NBF     41
#define B_CRYS  2048
#define EPSBN   1e-5f
#define GA      8                 // atoms per fused block
#define ROWS    (GA * M_NBR)      // 96 edge rows per block
#define GRID_F  (N_ATOMS / GA)    // 7500
#define WIMG_L  24576             // shorts per layer: [edge][self][nbr] x 8192
#define EROW    48                // shorts per edge row in Eimg (41 + bias + pad)
#define EP_ROWS (GRID_F * ROWS)   // 720000 edge rows total

// k_pre block partition: [0,288) wprep | [288,1248) embed | [1248,1257) bounds
#define PRE_WP   288
#define PRE_EMB  960
#define PRE_B    9
#define PRE_GRID (PRE_WP + PRE_EMB + PRE_B)

typedef __attribute__((ext_vector_type(8))) short bf8;
typedef __attribute__((ext_vector_type(4))) float f32x4;
#define MFMA_B16(a, b, c) __builtin_amdgcn_mfma_f32_16x16x32_bf16(a, b, c, 0, 0, 0)

__device__ __forceinline__ short f2bf(float f) {
  uint32_t u = __builtin_bit_cast(uint32_t, f);
  u += 0x7FFFu + ((u >> 16) & 1u);
  return (short)(u >> 16);
}
__device__ __forceinline__ float lo16(uint32_t u) {
  return __builtin_bit_cast(float, u << 16);
}
__device__ __forceinline__ float hi16(uint32_t u) {
  return __builtin_bit_cast(float, u & 0xFFFF0000u);
}
__device__ __forceinline__ float sp(float x) {
  return (x > 15.f) ? x : __logf(1.f + __expf(x));
}
__device__ __forceinline__ float sig(float x) {
  return 1.f / (1.f + __expf(-x));
}
__device__ __forceinline__ int lbound(const int* __restrict__ a, int n, int v) {
  int lo = 0, hi = n;
  while (lo < hi) {
    int mid = (lo + hi) >> 1;
    if (a[mid] < v) lo = mid + 1; else hi = mid;
  }
  return lo;
}
// pack (lo=f, hi=c) as two RNE bf16 in one dword; compiler emits
// v_cvt_pk_bf16_f32. Union pun (not __builtin_bit_cast: __hip_bfloat162
// has user-defined ctors -> not trivially copyable -> bit_cast rejected).
__device__ __forceinline__ unsigned int pkbf(float f, float c) {
  union { __hip_bfloat162 h; unsigned int u; } cv;
  cv.h = __float22bfloat162_rn(make_float2(f, c));
  return cv.u;
}

// ---------------------------------------------------------------------------
// MERGED PREP: wprep + embed2 + segment-bounds.
// wprep column mapping selectable: newmap=1 -> oc = jc (identity; flt cols
// in ct 0-3, core cols in ct 4-7 - lets the fused epilogue pack (flt,core)
// per-thread with one cvt_pk). newmap=0 -> legacy interleaved mapping for
// the k_fused4 fallback.
// ---------------------------------------------------------------------------
__global__ __launch_bounds__(256) void k_pre(
    const float* __restrict__ conv_W, const float* __restrict__ conv_b,
    const float* __restrict__ bn1_g, const float* __restrict__ bn1_b,
    unsigned short* __restrict__ Wimg, const float* __restrict__ A,
    const float* __restrict__ W, const float* __restrict__ bias,
    float* __restrict__ X, unsigned int* __restrict__ XbU,
    const int* __restrict__ seg, int* __restrict__ bounds, int newmap) {
  const int b = blockIdx.x;

  if (b < PRE_WP) {
    // ---------------- wprep ----------------
    const int gid = b * 256 + threadIdx.x;
    if (gid >= 3 * WIMG_L) return;
    const int layer = gid / WIMG_L, rem = gid % WIMG_L;
    const int which = rem / 8192, r2 = rem % 8192;
    const int frag = r2 >> 9, lane = (r2 >> 3) & 63, j = r2 & 7;
    const int ct = frag >> 1, ks = frag & 1;
    const int quad = lane >> 4, l15 = lane & 15;
    const int jc = ct * 16 + l15;
    const int oc = newmap ? jc : ((jc & 1) ? (jc >> 1) + 64 : (jc >> 1));
    const float s = bn1_g[layer * 128 + oc] * rsqrtf(1.f + EPSBN);
    const int k = ks * 32 + quad * 8 + j;
    const float* Wc = conv_W + (size_t)layer * 169 * 128;
    float v = 0.f;
    if (which == 0) {
      if (k < NBF) v = Wc[(128 + k) * 128 + oc] * s;
      else if (k == NBF)
        v = conv_b[layer * 128 + oc] * s + bn1_b[layer * 128 + oc];
    } else if (which == 1) {
      v = Wc[k * 128 + oc] * s;
    } else {
      v = Wc[(64 + k) * 128 + oc] * s;
    }
    Wimg[gid] = (unsigned short)f2bf(v);
    return;
  }

  if (b < PRE_WP + PRE_EMB) {
    // ---------------- embed2 ----------------
    const int lane = threadIdx.x & 63, wv = threadIdx.x >> 6;
    const int quad = lane >> 4, l15 = lane & 15;
    const int gw = (b - PRE_WP) * 4 + wv;
    const int nw = PRE_EMB * 4;
    bf8 Bf[3][4];
    float bs[4];
#pragma unroll
    for (int ct = 0; ct < 4; ++ct) {
      const int col = ct * 16 + l15;
      bs[ct] = bias[col];
#pragma unroll
      for (int ks = 0; ks < 3; ++ks) {
        bf8 bb;
#pragma unroll
        for (int i = 0; i < 8; ++i) {
          const int k = ks * 32 + quad * 8 + i;
          bb[i] = (k < 92) ? f2bf(W[k * 64 + col]) : (short)0;
        }
        Bf[ks][ct] = bb;
      }
    }
    for (int rt = gw; rt < 3750; rt += nw) {
      const int rbase = rt * 16;
      const float* ar = A + (size_t)(rbase + l15) * 92;
      const float4 p0 = *(const float4*)(ar + quad * 8);
      const float4 p1 = *(const float4*)(ar + quad * 8 + 4);
      const float4 p2 = *(const float4*)(ar + 32 + quad * 8);
      const float4 p3 = *(const float4*)(ar + 32 + quad * 8 + 4);
      bf8 A0, A1, A2;
      A0[0] = f2bf(p0.x); A0[1] = f2bf(p0.y); A0[2] = f2bf(p0.z); A0[3] = f2bf(p0.w);
      A0[4] = f2bf(p1.x); A0[5] = f2bf(p1.y); A0[6] = f2bf(p1.z); A0[7] = f2bf(p1.w);
      A1[0] = f2bf(p2.x); A1[1] = f2bf(p2.y); A1[2] = f2bf(p2.z); A1[3] = f2bf(p2.w);
      A1[4] = f2bf(p3.x); A1[5] = f2bf(p3.y); A1[6] = f2bf(p3.z); A1[7] = f2bf(p3.w);
#pragma unroll
      for (int i = 0; i < 8; ++i) {
        const int k = 64 + quad * 8 + i;
        A2[i] = (k < 92) ? f2bf(ar[k]) : (short)0;
      }
      const f32x4 z = {0.f, 0.f, 0.f, 0.f};
      f32x4 acc[4];
#pragma unroll
      for (int ct = 0; ct < 4; ++ct) {
        acc[ct] = MFMA_B16(A0, Bf[0][ct], z);
        acc[ct] = MFMA_B16(A1, Bf[1][ct], acc[ct]);
        acc[ct] = MFMA_B16(A2, Bf[2][ct], acc[ct]);
      }
#pragma unroll
      for (int ct = 0; ct < 4; ++ct)
#pragma unroll
        for (int r = 0; r < 4; ++r) {
          const int row = rbase + quad * 4 + r;
          const float v = acc[ct][r] + bs[ct];
          X[(size_t)row * 64 + ct * 16 + l15] = v;
          const unsigned int u = (unsigned short)f2bf(v);
          const unsigned int p = __shfl_xor((int)u, 1);
          if (!(l15 & 1))
            XbU[(size_t)row * 32 + ct * 8 + (l15 >> 1)] = u | (p << 16);
        }
    }
    return;
  }

  // ---------------- bounds: bounds[b] = lbound(seg, b), b in [0,2048] ------
  const int bi = (b - PRE_WP - PRE_EMB) * 256 + threadIdx.x;
  if (bi <= B_CRYS) bounds[bi] = lbound(seg, N_ATOMS, bi);
}

// ---------------------------------------------------------------------------
// FUSED conv LAYER 1 (fast path): edge A-fragments from f32 NF with bf16
// write-through to Eimg. MFMA loop: cp-pairs (flt=ct, core=ct+4 under the
// identity Wimg mapping) so the epilogue packs (flt,core) per thread with
// one v_cvt_pk_bf16_f32 + one b32 LDS write - no shfl.
// ---------------------------------------------------------------------------
__global__ __launch_bounds__(256, 5) void k_fused7(
    float* __restrict__ X, const unsigned short* __restrict__ XbIn,
    unsigned int* __restrict__ XbOutU, const float* __restrict__ NF,
    unsigned short* __restrict__ Eimg, const int* __restrict__ IDX,
    const unsigned short* __restrict__ Wi, const float* __restrict__ g2,
    const float* __restrict__ b2) {
  __shared__ __align__(16) unsigned int eb32[ROWS * 64];  // 24576 B
  const int tid = threadIdx.x;
  const int lane = tid & 63, wv = tid >> 6;
  const int quad = lane >> 4, l15 = lane & 15;
  const int g = blockIdx.x;
  const int ntile = (wv < 2) ? 2 : 1;  // 6 row-tiles over 4 waves

  // ---- neighbor/self gathers + edge from NF (+ Eimg write-through) ----
  bf8 Ax0[2], Ax1[2], As0[2], As1[2], Ae0[2], Ae1[2];
#pragma unroll
  for (int ti = 0; ti < 2; ++ti) {
    if (ti < ntile) {
      const int rbase = (wv + ti * 4) * 16;
      const int er = g * ROWS + rbase + l15;
      const int jr = IDX[er];
      const unsigned short* xr = XbIn + (size_t)jr * 64 + quad * 8;
      Ax0[ti] = *(const bf8*)xr;
      Ax1[ti] = *(const bf8*)(xr + 32);
      const int arow = g * GA + (rbase + l15) / M_NBR;
      const unsigned short* sr = XbIn + (size_t)arow * 64 + quad * 8;
      As0[ti] = *(const bf8*)sr;
      As1[ti] = *(const bf8*)(sr + 32);

      const float* rp = NF + (size_t)er * NBF;
      bf8 a0, a1;
      const float4 q0 = *(const float4*)(rp + quad * 8);
      const float4 q1 = *(const float4*)(rp + quad * 8 + 4);
      a0[0] = f2bf(q0.x); a0[1] = f2bf(q0.y); a0[2] = f2bf(q0.z); a0[3] = f2bf(q0.w);
      a0[4] = f2bf(q1.x); a0[5] = f2bf(q1.y); a0[6] = f2bf(q1.z); a0[7] = f2bf(q1.w);
      if (quad == 0) {
        const float4 q2 = *(const float4*)(rp + 32);
        const float4 q3 = *(const float4*)(rp + 36);
        a1[0] = f2bf(q2.x); a1[1] = f2bf(q2.y); a1[2] = f2bf(q2.z); a1[3] = f2bf(q2.w);
        a1[4] = f2bf(q3.x); a1[5] = f2bf(q3.y); a1[6] = f2bf(q3.z); a1[7] = f2bf(q3.w);
      } else if (quad == 1) {
        a1[0] = f2bf(rp[40]);     // scalar: no overrun on last row
        a1[1] = (short)0x3F80;    // bf16 1.0 at k=41 -> multiplies bias row
#pragma unroll
        for (int i = 2; i < 8; ++i) a1[i] = 0;
      } else {
#pragma unroll
        for (int i = 0; i < 8; ++i) a1[i] = 0;
      }
      Ae0[ti] = a0;
      Ae1[ti] = a1;
      // write-through for layers 2-3 (layout == old eprep output)
      unsigned short* op = Eimg + (size_t)er * EROW;
      *(bf8*)(op + quad * 8) = a0;
      if (quad < 2) *(bf8*)(op + 32 + quad * 8) = a1;
    }
  }

  // ---- early X loads for the tail ----
  float xpre[2];
#pragma unroll
  for (int al = 0; al < 2; ++al)
    xpre[al] = X[(size_t)(g * GA + wv * 2 + al) * 64 + lane];

  // ---- MFMA: cp outer (flt+core fragment pairs), ti inner ----
  const f32x4 z = {0.f, 0.f, 0.f, 0.f};
#pragma unroll 1
  for (int cp = 0; cp < 4; ++cp) {
    const unsigned short* wf = Wi + cp * 1024 + lane * 8;        // flt ct=cp
    const unsigned short* wc = Wi + (cp + 4) * 1024 + lane * 8;  // core ct=cp+4
    const bf8 BeF0 = *(const bf8*)(wf);
    const bf8 BeF1 = *(const bf8*)(wf + 512);
    const bf8 BsF0 = *(const bf8*)(wf + 8192);
    const bf8 BsF1 = *(const bf8*)(wf + 8192 + 512);
    const bf8 BnF0 = *(const bf8*)(wf + 16384);
    const bf8 BnF1 = *(const bf8*)(wf + 16384 + 512);
    const bf8 BeC0 = *(const bf8*)(wc);
    const bf8 BeC1 = *(const bf8*)(wc + 512);
    const bf8 BsC0 = *(const bf8*)(wc + 8192);
    const bf8 BsC1 = *(const bf8*)(wc + 8192 + 512);
    const bf8 BnC0 = *(const bf8*)(wc + 16384);
    const bf8 BnC1 = *(const bf8*)(wc + 16384 + 512);
#pragma unroll
    for (int ti = 0; ti < 2; ++ti) {
      if (ti < ntile) {
        const int rbase = (wv + ti * 4) * 16;
        f32x4 aF = MFMA_B16(Ax0[ti], BnF0, z);
        aF = MFMA_B16(Ax1[ti], BnF1, aF);
        aF = MFMA_B16(As0[ti], BsF0, aF);
        aF = MFMA_B16(As1[ti], BsF1, aF);
        aF = MFMA_B16(Ae0[ti], BeF0, aF);
        aF = MFMA_B16(Ae1[ti], BeF1, aF);
        f32x4 aC = MFMA_B16(Ax0[ti], BnC0, z);
        aC = MFMA_B16(Ax1[ti], BnC1, aC);
        aC = MFMA_B16(As0[ti], BsC0, aC);
        aC = MFMA_B16(As1[ti], BsC1, aC);
        aC = MFMA_B16(Ae0[ti], BeC0, aC);
        aC = MFMA_B16(Ae1[ti], BeC1, aC);
        const int c = cp * 16 + l15;
#pragma unroll
        for (int r = 0; r < 4; ++r) {
          const int row = rbase + quad * 4 + r;
          eb32[row * 64 + ((c + row) & 63)] = pkbf(aF[r], aC[r]);
        }
      }
    }
  }
  __syncthreads();

  // ---- tail ----
  const float inv = rsqrtf(1.f + EPSBN);
  const float s2 = g2[lane] * inv, o2 = b2[lane];
#pragma unroll
  for (int al = 0; al < 2; ++al) {
    const int a_local = wv * 2 + al;
    const int n = g * GA + a_local;
    float acc = 0.f;
#pragma unroll
    for (int m = 0; m < 12; ++m) {
      const int row = a_local * 12 + m;
      const uint32_t eu = eb32[row * 64 + ((lane + row) & 63)];
      acc += sig(lo16(eu)) * sp(hi16(eu));
    }
    const size_t o = (size_t)n * 64 + lane;
    const float res = sp(xpre[al] + acc * s2 + o2);
    X[o] = res;
    const unsigned int u = (unsigned short)f2bf(res);
    const unsigned int p = __shfl_xor((int)u, 1);
    if (!(lane & 1)) XbOutU[(size_t)n * 32 + (lane >> 1)] = u | (p << 16);
  }
}

// ---------------------------------------------------------------------------
// FUSED conv layers 2-3, FAST PATH: same cp-pair MFMA loop, edge from Eimg.
// ---------------------------------------------------------------------------
__global__ __launch_bounds__(256, 5) void k_fused6(
    float* __restrict__ X, const unsigned short* __restrict__ XbIn,
    unsigned int* __restrict__ XbOutU, const unsigned short* __restrict__ Eimg,
    const int* __restrict__ IDX, const unsigned short* __restrict__ Wi,
    const float* __restrict__ g2, const float* __restrict__ b2) {
  __shared__ __align__(16) unsigned int eb32[ROWS * 64];  // 24576 B
  const int tid = threadIdx.x;
  const int lane = tid & 63, wv = tid >> 6;
  const int quad = lane >> 4, l15 = lane & 15;
  const int g = blockIdx.x;
  const int ntile = (wv < 2) ? 2 : 1;  // 6 row-tiles over 4 waves

  bf8 Ax0[2], Ax1[2], As0[2], As1[2], Ae0[2], Ae1[2];
#pragma unroll
  for (int ti = 0; ti < 2; ++ti) {
    if (ti < ntile) {
      const int rbase = (wv + ti * 4) * 16;
      const int er = g * ROWS + rbase + l15;
      const int jr = IDX[er];
      const unsigned short* xr = XbIn + (size_t)jr * 64 + quad * 8;
      Ax0[ti] = *(const bf8*)xr;
      Ax1[ti] = *(const bf8*)(xr + 32);
      const int arow = g * GA + (rbase + l15) / M_NBR;
      const unsigned short* sr = XbIn + (size_t)arow * 64 + quad * 8;
      As0[ti] = *(const bf8*)sr;
      As1[ti] = *(const bf8*)(sr + 32);
      const unsigned short* ep = Eimg + (size_t)er * EROW;
      Ae0[ti] = *(const bf8*)(ep + quad * 8);
      bf8 a1;
#pragma unroll
      for (int i = 0; i < 8; ++i) a1[i] = 0;
      if (quad < 2) a1 = *(const bf8*)(ep + 32 + quad * 8);
      Ae1[ti] = a1;
    }
  }

  float xpre[2];
#pragma unroll
  for (int al = 0; al < 2; ++al)
    xpre[al] = X[(size_t)(g * GA + wv * 2 + al) * 64 + lane];

  const f32x4 z = {0.f, 0.f, 0.f, 0.f};
#pragma unroll 1
  for (int cp = 0; cp < 4; ++cp) {
    const unsigned short* wf = Wi + cp * 1024 + lane * 8;
    const unsigned short* wc = Wi + (cp + 4) * 1024 + lane * 8;
    const bf8 BeF0 = *(const bf8*)(wf);
    const bf8 BeF1 = *(const bf8*)(wf + 512);
    const bf8 BsF0 = *(const bf8*)(wf + 8192);
    const bf8 BsF1 = *(const bf8*)(wf + 8192 + 512);
    const bf8 BnF0 = *(const bf8*)(wf + 16384);
    const bf8 BnF1 = *(const bf8*)(wf + 16384 + 512);
    const bf8 BeC0 = *(const bf8*)(wc);
    const bf8 BeC1 = *(const bf8*)(wc + 512);
    const bf8 BsC0 = *(const bf8*)(wc + 8192);
    const bf8 BsC1 = *(const bf8*)(wc + 8192 + 512);
    const bf8 BnC0 = *(const bf8*)(wc + 16384);
    const bf8 BnC1 = *(const bf8*)(wc + 16384 + 512);
#pragma unroll
    for (int ti = 0; ti < 2; ++ti) {
      if (ti < ntile) {
        const int rbase = (wv + ti * 4) * 16;
        f32x4 aF = MFMA_B16(Ax0[ti], BnF0, z);
        aF = MFMA_B16(Ax1[ti], BnF1, aF);
        aF = MFMA_B16(As0[ti], BsF0, aF);
        aF = MFMA_B16(As1[ti], BsF1, aF);
        aF = MFMA_B16(Ae0[ti], BeF0, aF);
        aF = MFMA_B16(Ae1[ti], BeF1, aF);
        f32x4 aC = MFMA_B16(Ax0[ti], BnC0, z);
        aC = MFMA_B16(Ax1[ti], BnC1, aC);
        aC = MFMA_B16(As0[ti], BsC0, aC);
        aC = MFMA_B16(As1[ti], BsC1, aC);
        aC = MFMA_B16(Ae0[ti], BeC0, aC);
        aC = MFMA_B16(Ae1[ti], BeC1, aC);
        const int c = cp * 16 + l15;
#pragma unroll
        for (int r = 0; r < 4; ++r) {
          const int row = rbase + quad * 4 + r;
          eb32[row * 64 + ((c + row) & 63)] = pkbf(aF[r], aC[r]);
        }
      }
    }
  }
  __syncthreads();

  const float inv = rsqrtf(1.f + EPSBN);
  const float s2 = g2[lane] * inv, o2 = b2[lane];
#pragma unroll
  for (int al = 0; al < 2; ++al) {
    const int a_local = wv * 2 + al;
    const int n = g * GA + a_local;
    float acc = 0.f;
#pragma unroll
    for (int m = 0; m < 12; ++m) {
      const int row = a_local * 12 + m;
      const uint32_t eu = eb32[row * 64 + ((lane + row) & 63)];
      acc += sig(lo16(eu)) * sp(hi16(eu));
    }
    const size_t o = (size_t)n * 64 + lane;
    const float res = sp(xpre[al] + acc * s2 + o2);
    X[o] = res;
    const unsigned int u = (unsigned short)f2bf(res);
    const unsigned int p = __shfl_xor((int)u, 1);
    if (!(lane & 1)) XbOutU[(size_t)n * 32 + (lane >> 1)] = u | (p << 16);
  }
}

// ---------------------------------------------------------------------------
// FUSED conv layer, FALLBACK: verbatim R0 kernel (legacy Wimg mapping).
// ---------------------------------------------------------------------------
__global__ __launch_bounds__(256, 5) void k_fused4(
    float* __restrict__ X, const unsigned short* __restrict__ XbIn,
    unsigned int* __restrict__ XbOutU, const float* __restrict__ NF,
    const int* __restrict__ IDX, const unsigned short* __restrict__ Wi,
    const float* __restrict__ g2, const float* __restrict__ b2) {
  __shared__ __align__(16) unsigned int eb32[ROWS * 64];  // 24576 B
  unsigned short* eb16 = (unsigned short*)eb32;
  float* stage = (float*)eb32;  // first 3936 floats = 96x41 tile
  const int tid = threadIdx.x;
  const int lane = tid & 63, wv = tid >> 6;
  const int quad = lane >> 4, l15 = lane & 15;
  const int g = blockIdx.x;
  const int ntile = (wv < 2) ? 2 : 1;  // 6 row-tiles over 4 waves

  bf8 Ax0[2], Ax1[2], As0[2], As1[2];
#pragma unroll
  for (int ti = 0; ti < 2; ++ti) {
    if (ti < ntile) {
      const int rbase = (wv + ti * 4) * 16;
      const int jr = IDX[g * ROWS + rbase + l15];
      const unsigned short* xr = XbIn + (size_t)jr * 64 + quad * 8;
      Ax0[ti] = *(const bf8*)xr;
      Ax1[ti] = *(const bf8*)(xr + 32);
      const int arow = g * GA + (rbase + l15) / M_NBR;
      const unsigned short* sr = XbIn + (size_t)arow * 64 + quad * 8;
      As0[ti] = *(const bf8*)sr;
      As1[ti] = *(const bf8*)(sr + 32);
    }
  }

  const float4* s4 = (const float4*)(NF + (size_t)g * (ROWS * NBF));
#pragma unroll
  for (int it = 0; it < 4; ++it) {
    const int w = tid + it * 256;
    if (w < (ROWS * NBF) / 4) ((float4*)stage)[w] = s4[w];
  }
  __syncthreads();

  bf8 Ae0[2], Ae1[2];
#pragma unroll
  for (int ti = 0; ti < 2; ++ti) {
    if (ti < ntile) {
      const int rbase = (wv + ti * 4) * 16;
      const float* rp = stage + (rbase + l15) * NBF;
      bf8 a0, a1;
#pragma unroll
      for (int i = 0; i < 8; ++i) a0[i] = f2bf(rp[quad * 8 + i]);
      if (quad == 0) {
#pragma unroll
        for (int i = 0; i < 8; ++i) a1[i] = f2bf(rp[32 + i]);
      } else if (quad == 1) {
        a1[0] = f2bf(rp[40]);
        a1[1] = (short)0x3F80;  // bf16 1.0 at k=41 -> multiplies bias row
#pragma unroll
        for (int i = 2; i < 8; ++i) a1[i] = 0;
      } else {
#pragma unroll
        for (int i = 0; i < 8; ++i) a1[i] = 0;
      }
      Ae0[ti] = a0;
      Ae1[ti] = a1;
    }
  }
  __syncthreads();

#pragma unroll
  for (int ti = 0; ti < 2; ++ti) {
    if (ti < ntile) {
      const int rbase = (wv + ti * 4) * 16;
      const f32x4 z = {0.f, 0.f, 0.f, 0.f};
#pragma unroll 1
      for (int ct = 0; ct < 8; ++ct) {
        const bf8 Be0 = *(const bf8*)(Wi + ((ct * 2 + 0) * 64 + lane) * 8);
        const bf8 Be1 = *(const bf8*)(Wi + ((ct * 2 + 1) * 64 + lane) * 8);
        const bf8 Bs0 =
            *(const bf8*)(Wi + 8192 + ((ct * 2 + 0) * 64 + lane) * 8);
        const bf8 Bs1 =
            *(const bf8*)(Wi + 8192 + ((ct * 2 + 1) * 64 + lane) * 8);
        const bf8 Bn0 =
            *(const bf8*)(Wi + 16384 + ((ct * 2 + 0) * 64 + lane) * 8);
        const bf8 Bn1 =
            *(const bf8*)(Wi + 16384 + ((ct * 2 + 1) * 64 + lane) * 8);
        f32x4 acc = MFMA_B16(Ax0[ti], Bn0, z);
        acc = MFMA_B16(Ax1[ti], Bn1, acc);
        acc = MFMA_B16(As0[ti], Bs0, acc);
        acc = MFMA_B16(As1[ti], Bs1, acc);
        acc = MFMA_B16(Ae0[ti], Be0, acc);
        acc = MFMA_B16(Ae1[ti], Be1, acc);
        const int j = ct * 16 + l15;
        const int c = j >> 1, h = j & 1;
#pragma unroll
        for (int r = 0; r < 4; ++r) {
          const int row = rbase + quad * 4 + r;
          eb16[row * 128 + ((c + row) & 63) * 2 + h] =
              (unsigned short)f2bf(acc[r]);
        }
      }
    }
  }
  __syncthreads();

  const float inv = rsqrtf(1.f + EPSBN);
  const float s2 = g2[lane] * inv, o2 = b2[lane];
#pragma unroll
  for (int al = 0; al < 2; ++al) {
    const int a_local = wv * 2 + al;
    const int n = g * GA + a_local;
    float acc = 0.f;
#pragma unroll
    for (int m = 0; m < 12; ++m) {
      const int row = a_local * 12 + m;
      const uint32_t eu = eb32[row * 64 + ((lane + row) & 63)];
      acc += sig(lo16(eu)) * sp(hi16(eu));
    }
    const size_t o = (size_t)n * 64 + lane;
    const float res = sp(X[o] + acc * s2 + o2);
    X[o] = res;
    const unsigned int u = (unsigned short)f2bf(res);
    const unsigned int p = __shfl_xor((int)u, 1);
    if (!(lane & 1)) XbOutU[(size_t)n * 32 + (lane >> 1)] = u | (p << 16);
  }
}

// ---------------------------------------------------------------------------
// Head: pooling with precomputed bounds, 256 threads (verbatim R8).
// ---------------------------------------------------------------------------
__global__ __launch_bounds__(256) void k_head(
    const float* __restrict__ Xf, const int* __restrict__ bounds,
    const float* __restrict__ EF, const float* __restrict__ Wx,
    const float* __restrict__ bx, const float* __restrict__ gx,
    const float* __restrict__ bxb, const float* __restrict__ Wfc,
    const float* __restrict__ bfc, const float* __restrict__ Wo0,
    const float* __restrict__ bo0, const float* __restrict__ Wo1,
    const float* __restrict__ bo1, const float* __restrict__ Wo2,
    const float* __restrict__ bo2, float* __restrict__ out) {
  const int b = blockIdx.x;
  const int t = threadIdx.x;
  __shared__ float vbuf[80];
  __shared__ float part[256];
  __shared__ float4 r4[128];
  const int lo = bounds[b];
  const int hi = bounds[b + 1];
  const int col = t & 63, qq = t >> 6;  // 4-way over rows
  float s = 0.f;
  for (int r = lo + qq; r < hi; r += 4) s += Xf[(size_t)r * 64 + col];
  part[t] = s;
  __syncthreads();
  if (t < 64) {
    vbuf[t] = (part[t] + part[t + 64] + part[t + 128] + part[t + 192]) /
              fmaxf((float)(hi - lo), 1.f);
  } else if (t < 80) {
    const int e = t - 64;
    float a = bx[e];
#pragma unroll
    for (int k = 0; k < 8; ++k) a += EF[b * 8 + k] * Wx[k * 16 + e];
    a = a * (gx[e] * rsqrtf(1.f + EPSBN)) + bxb[e];
    vbuf[t] = sp(a);
  }
  __syncthreads();
  if (t < 128) {
    float h = bfc[t];
#pragma unroll
    for (int k = 0; k < 80; ++k) h += vbuf[k] * Wfc[k * 128 + t];
    h = sp(h);
    r4[t] = make_float4(h * Wo0[t], h * Wo1[2 * t], h * Wo1[2 * t + 1],
                        h * Wo2[t]);
  }
  __syncthreads();
  for (int st2 = 64; st2 > 0; st2 >>= 1) {
    if (t < st2) {
      float4 a = r4[t], c = r4[t + st2];
      r4[t] = make_float4(a.x + c.x, a.y + c.y, a.z + c.z, a.w + c.w);
    }
    __syncthreads();
  }
  if (t == 0) {
    float4 r = r4[0];
    out[b] = r.x + bo0[0];
    float z0 = r.y + bo1[0], z1 = r.z + bo1[1];
    float mx = fmaxf(z0, z1);
    float lse = mx + __logf(__expf(z0 - mx) + __expf(z1 - mx));
    out[B_CRYS + 2 * b] = z0 - lse;
    out[B_CRYS + 2 * b + 1] = z1 - lse;
    out[3 * B_CRYS + b] = r.w + bo2[0];
  }
}

// ---------------------------------------------------------------------------
extern "C" void kernel_launch(void* const* d_in, const int* in_sizes, int n_in,
                              void* d_out, int out_size, void* d_ws,
                              size_t ws_size, hipStream_t stream) {
  const float* atom_fea = (const float*)d_in[0];
  const float* nbr_fea  = (const float*)d_in[1];
  const int*   nbr_idx  = (const int*)d_in[2];
  const int*   seg      = (const int*)d_in[3];
  const float* extra    = (const float*)d_in[4];
  const float* W_embed  = (const float*)d_in[5];
  const float* b_embed  = (const float*)d_in[6];
  const float* conv_W   = (const float*)d_in[7];
  const float* conv_b   = (const float*)d_in[8];
  const float* bn1_g    = (const float*)d_in[9];
  const float* bn1_b    = (const float*)d_in[10];
  const float* bn2_g    = (const float*)d_in[11];
  const float* bn2_b    = (const float*)d_in[12];
  const float* W_extra  = (const float*)d_in[13];
  const float* b_extra  = (const float*)d_in[14];
  const float* bnx_g    = (const float*)d_in[15];
  const float* bnx_b    = (const float*)d_in[16];
  const float* W_fc     = (const float*)d_in[17];
  const float* b_fc     = (const float*)d_in[18];
  const float* W_out0   = (const float*)d_in[19];
  const float* b_out0   = (const float*)d_in[20];
  const float* W_out1   = (const float*)d_in[21];
  const float* b_out1   = (const float*)d_in[22];
  const float* W_out2   = (const float*)d_in[23];
  const float* b_out2   = (const float*)d_in[24];
  float* out = (float*)d_out;

  // ws layout: X f32 | XbU0 | XbU1 | Wimg | bounds | [Eimg if it fits]
  float* x = (float*)d_ws;
  unsigned int* xbu0 = (unsigned int*)(x + (size_t)N_ATOMS * 64);
  unsigned int* xbu1 = xbu0 + (size_t)N_ATOMS * 32;
  unsigned short* Wimg = (unsigned short*)(xbu1 + (size_t)N_ATOMS * 32);
  int* bounds = (int*)(Wimg + (size_t)3 * WIMG_L);
  unsigned short* Eimg = (unsigned short*)(bounds + 2052);  // 16B-aligned

  const size_t base_bytes =
      (size_t)N_ATOMS * 64 * 4 + (size_t)N_ATOMS * 32 * 4 * 2 +
      (size_t)3 * WIMG_L * 2 + 2052 * 4;
  const size_t eimg_bytes = (size_t)EP_ROWS * EROW * 2;  // 69.12 MB
  const bool use_eimg = (ws_size >= base_bytes + eimg_bytes);

  hipLaunchKernelGGL(k_pre, dim3(PRE_GRID), dim3(256), 0, stream, conv_W,
                     conv_b, bn1_g, bn1_b, Wimg, atom_fea, W_embed, b_embed, x,
                     xbu0, seg, bounds, (int)use_eimg);

  unsigned int* xin = xbu0;
  unsigned int* xout = xbu1;
  for (int i = 0; i < 3; ++i) {
    if (use_eimg) {
      if (i == 0) {
        hipLaunchKernelGGL(k_fused7, dim3(GRID_F), dim3(256), 0, stream, x,
                           (const unsigned short*)xin, xout, nbr_fea, Eimg,
                           nbr_idx, Wimg + (size_t)i * WIMG_L, bn2_g + i * 64,
                           bn2_b + i * 64);
      } else {
        hipLaunchKernelGGL(k_fused6, dim3(GRID_F), dim3(256), 0, stream, x,
                           (const unsigned short*)xin, xout, Eimg, nbr_idx,
                           Wimg + (size_t)i * WIMG_L, bn2_g + i * 64,
                           bn2_b + i * 64);
      }
    } else {
      hipLaunchKernelGGL(k_fused4, dim3(GRID_F), dim3(256), 0, stream, x,
                         (const unsigned short*)xin, xout, nbr_fea, nbr_idx,
                         Wimg + (size_t)i * WIMG_L, bn2_g + i * 64,
                         bn2_b + i * 64);
    }
    unsigned int* tmp = xin;
    xin = xout;
    xout = tmp;
  }
  hipLaunchKernelGGL(k_head, dim3(B_CRYS), dim3(256), 0, stream, x, bounds,
                     extra, W_extra, b_extra, bnx_g, bnx_b, W_fc, b_fc, W_out0,
                     b_out0, W_out1, b_out1, W_out2, b_out2, out);
}

// Round 13
// 506.346 us; speedup vs baseline: 1.6026x; 1.6026x over previous
//
#include <hip/hip_runtime.h>
#include <hip/hip_bf16.h>
#include <math.h>
#include <stdint.h>

#define N_ATOMS 60000
#define M_NBR   12
#define NBF     41
#define B_CRYS  2048
#define EPSBN   1e-5f
#define GA      8                 // atoms per fused block
#define ROWS    (GA * M_NBR)      // 96 edge rows per block
#define GRID_F  (N_ATOMS / GA)    // 7500
#define WIMG_L  24576             // shorts per layer: [edge][self][nbr] x 8192
#define EROW    48                // shorts per edge row in Eimg (41 + bias + pad)
#define EP_ROWS (GRID_F * ROWS)   // 720000 edge rows total

// k_pre block partition: [0,288) wprep | [288,1248) embed | [1248,1257) bounds
#define PRE_WP   288
#define PRE_EMB  960
#define PRE_B    9
#define PRE_GRID (PRE_WP + PRE_EMB + PRE_B)

typedef __attribute__((ext_vector_type(8))) short bf8;
typedef __attribute__((ext_vector_type(4))) float f32x4;
#define MFMA_B16(a, b, c) __builtin_amdgcn_mfma_f32_16x16x32_bf16(a, b, c, 0, 0, 0)

__device__ __forceinline__ short f2bf(float f) {
  uint32_t u = __builtin_bit_cast(uint32_t, f);
  u += 0x7FFFu + ((u >> 16) & 1u);
  return (short)(u >> 16);
}
__device__ __forceinline__ float lo16(uint32_t u) {
  return __builtin_bit_cast(float, u << 16);
}
__device__ __forceinline__ float hi16(uint32_t u) {
  return __builtin_bit_cast(float, u & 0xFFFF0000u);
}
__device__ __forceinline__ float sp(float x) {
  return (x > 15.f) ? x : __logf(1.f + __expf(x));
}
__device__ __forceinline__ float sig(float x) {
  return 1.f / (1.f + __expf(-x));
}
__device__ __forceinline__ int lbound(const int* __restrict__ a, int n, int v) {
  int lo = 0, hi = n;
  while (lo < hi) {
    int mid = (lo + hi) >> 1;
    if (a[mid] < v) lo = mid + 1; else hi = mid;
  }
  return lo;
}
// pack two RNE bf16 in one dword (lo=a, hi=b); compiler emits
// v_cvt_pk_bf16_f32. Union pun (bit_cast rejects __hip_bfloat162: has
// user-defined ctors). Verified bit-identical to f2bf (R12 passed).
__device__ __forceinline__ unsigned int pkbf(float a, float b) {
  union { __hip_bfloat162 h; unsigned int u; } cv;
  cv.h = __float22bfloat162_rn(make_float2(a, b));
  return cv.u;
}

// ---------------------------------------------------------------------------
// MERGED PREP: wprep + embed2 + segment-bounds (verbatim R10, legacy map).
// ---------------------------------------------------------------------------
__global__ __launch_bounds__(256) void k_pre(
    const float* __restrict__ conv_W, const float* __restrict__ conv_b,
    const float* __restrict__ bn1_g, const float* __restrict__ bn1_b,
    unsigned short* __restrict__ Wimg, const float* __restrict__ A,
    const float* __restrict__ W, const float* __restrict__ bias,
    float* __restrict__ X, unsigned int* __restrict__ XbU,
    const int* __restrict__ seg, int* __restrict__ bounds) {
  const int b = blockIdx.x;

  if (b < PRE_WP) {
    // ---------------- wprep ----------------
    const int gid = b * 256 + threadIdx.x;
    if (gid >= 3 * WIMG_L) return;
    const int layer = gid / WIMG_L, rem = gid % WIMG_L;
    const int which = rem / 8192, r2 = rem % 8192;
    const int frag = r2 >> 9, lane = (r2 >> 3) & 63, j = r2 & 7;
    const int ct = frag >> 1, ks = frag & 1;
    const int quad = lane >> 4, l15 = lane & 15;
    const int jc = ct * 16 + l15;
    const int oc = (jc & 1) ? (jc >> 1) + 64 : (jc >> 1);
    const float s = bn1_g[layer * 128 + oc] * rsqrtf(1.f + EPSBN);
    const int k = ks * 32 + quad * 8 + j;
    const float* Wc = conv_W + (size_t)layer * 169 * 128;
    float v = 0.f;
    if (which == 0) {
      if (k < NBF) v = Wc[(128 + k) * 128 + oc] * s;
      else if (k == NBF)
        v = conv_b[layer * 128 + oc] * s + bn1_b[layer * 128 + oc];
    } else if (which == 1) {
      v = Wc[k * 128 + oc] * s;
    } else {
      v = Wc[(64 + k) * 128 + oc] * s;
    }
    Wimg[gid] = (unsigned short)f2bf(v);
    return;
  }

  if (b < PRE_WP + PRE_EMB) {
    // ---------------- embed2 ----------------
    const int lane = threadIdx.x & 63, wv = threadIdx.x >> 6;
    const int quad = lane >> 4, l15 = lane & 15;
    const int gw = (b - PRE_WP) * 4 + wv;
    const int nw = PRE_EMB * 4;
    bf8 Bf[3][4];
    float bs[4];
#pragma unroll
    for (int ct = 0; ct < 4; ++ct) {
      const int col = ct * 16 + l15;
      bs[ct] = bias[col];
#pragma unroll
      for (int ks = 0; ks < 3; ++ks) {
        bf8 bb;
#pragma unroll
        for (int i = 0; i < 8; ++i) {
          const int k = ks * 32 + quad * 8 + i;
          bb[i] = (k < 92) ? f2bf(W[k * 64 + col]) : (short)0;
        }
        Bf[ks][ct] = bb;
      }
    }
    for (int rt = gw; rt < 3750; rt += nw) {
      const int rbase = rt * 16;
      const float* ar = A + (size_t)(rbase + l15) * 92;
      const float4 p0 = *(const float4*)(ar + quad * 8);
      const float4 p1 = *(const float4*)(ar + quad * 8 + 4);
      const float4 p2 = *(const float4*)(ar + 32 + quad * 8);
      const float4 p3 = *(const float4*)(ar + 32 + quad * 8 + 4);
      bf8 A0, A1, A2;
      A0[0] = f2bf(p0.x); A0[1] = f2bf(p0.y); A0[2] = f2bf(p0.z); A0[3] = f2bf(p0.w);
      A0[4] = f2bf(p1.x); A0[5] = f2bf(p1.y); A0[6] = f2bf(p1.z); A0[7] = f2bf(p1.w);
      A1[0] = f2bf(p2.x); A1[1] = f2bf(p2.y); A1[2] = f2bf(p2.z); A1[3] = f2bf(p2.w);
      A1[4] = f2bf(p3.x); A1[5] = f2bf(p3.y); A1[6] = f2bf(p3.z); A1[7] = f2bf(p3.w);
#pragma unroll
      for (int i = 0; i < 8; ++i) {
        const int k = 64 + quad * 8 + i;
        A2[i] = (k < 92) ? f2bf(ar[k]) : (short)0;
      }
      const f32x4 z = {0.f, 0.f, 0.f, 0.f};
      f32x4 acc[4];
#pragma unroll
      for (int ct = 0; ct < 4; ++ct) {
        acc[ct] = MFMA_B16(A0, Bf[0][ct], z);
        acc[ct] = MFMA_B16(A1, Bf[1][ct], acc[ct]);
        acc[ct] = MFMA_B16(A2, Bf[2][ct], acc[ct]);
      }
#pragma unroll
      for (int ct = 0; ct < 4; ++ct)
#pragma unroll
        for (int r = 0; r < 4; ++r) {
          const int row = rbase + quad * 4 + r;
          const float v = acc[ct][r] + bs[ct];
          X[(size_t)row * 64 + ct * 16 + l15] = v;
          const unsigned int u = (unsigned short)f2bf(v);
          const unsigned int p = __shfl_xor((int)u, 1);
          if (!(l15 & 1))
            XbU[(size_t)row * 32 + ct * 8 + (l15 >> 1)] = u | (p << 16);
        }
    }
    return;
  }

  // ---------------- bounds: bounds[b] = lbound(seg, b), b in [0,2048] ------
  const int bi = (b - PRE_WP - PRE_EMB) * 256 + threadIdx.x;
  if (bi <= B_CRYS) bounds[bi] = lbound(seg, N_ATOMS, bi);
}

// ---------------------------------------------------------------------------
// FUSED conv LAYER 1 (fast path): R10 structure (ct-outer Wi reuse, legacy
// interleaved mapping, edge from NF + Eimg write-through). R13 delta: the
// epilogue converts acc[r],acc[r+1] with ONE v_cvt_pk_bf16_f32 (rows r and
// r+1 get lo/hi halves) - same LDS bytes, ~190 fewer VALU ops/thread, zero
// extra register pressure (R12's cp-pair spilled to scratch; this doesn't).
// ---------------------------------------------------------------------------
__global__ __launch_bounds__(256, 5) void k_fused7(
    float* __restrict__ X, const unsigned short* __restrict__ XbIn,
    unsigned int* __restrict__ XbOutU, const float* __restrict__ NF,
    unsigned short* __restrict__ Eimg, const int* __restrict__ IDX,
    const unsigned short* __restrict__ Wi, const float* __restrict__ g2,
    const float* __restrict__ b2) {
  __shared__ __align__(16) unsigned int eb32[ROWS * 64];  // 24576 B
  unsigned short* eb16 = (unsigned short*)eb32;
  const int tid = threadIdx.x;
  const int lane = tid & 63, wv = tid >> 6;
  const int quad = lane >> 4, l15 = lane & 15;
  const int g = blockIdx.x;
  const int ntile = (wv < 2) ? 2 : 1;  // 6 row-tiles over 4 waves

  // ---- neighbor/self gathers + edge from NF (+ Eimg write-through) ----
  bf8 Ax0[2], Ax1[2], As0[2], As1[2], Ae0[2], Ae1[2];
#pragma unroll
  for (int ti = 0; ti < 2; ++ti) {
    if (ti < ntile) {
      const int rbase = (wv + ti * 4) * 16;
      const int er = g * ROWS + rbase + l15;
      const int jr = IDX[er];
      const unsigned short* xr = XbIn + (size_t)jr * 64 + quad * 8;
      Ax0[ti] = *(const bf8*)xr;
      Ax1[ti] = *(const bf8*)(xr + 32);
      const int arow = g * GA + (rbase + l15) / M_NBR;
      const unsigned short* sr = XbIn + (size_t)arow * 64 + quad * 8;
      As0[ti] = *(const bf8*)sr;
      As1[ti] = *(const bf8*)(sr + 32);

      const float* rp = NF + (size_t)er * NBF;
      bf8 a0, a1;
      const float4 q0 = *(const float4*)(rp + quad * 8);
      const float4 q1 = *(const float4*)(rp + quad * 8 + 4);
      a0[0] = f2bf(q0.x); a0[1] = f2bf(q0.y); a0[2] = f2bf(q0.z); a0[3] = f2bf(q0.w);
      a0[4] = f2bf(q1.x); a0[5] = f2bf(q1.y); a0[6] = f2bf(q1.z); a0[7] = f2bf(q1.w);
      if (quad == 0) {
        const float4 q2 = *(const float4*)(rp + 32);
        const float4 q3 = *(const float4*)(rp + 36);
        a1[0] = f2bf(q2.x); a1[1] = f2bf(q2.y); a1[2] = f2bf(q2.z); a1[3] = f2bf(q2.w);
        a1[4] = f2bf(q3.x); a1[5] = f2bf(q3.y); a1[6] = f2bf(q3.z); a1[7] = f2bf(q3.w);
      } else if (quad == 1) {
        a1[0] = f2bf(rp[40]);     // scalar: no overrun on last row
        a1[1] = (short)0x3F80;    // bf16 1.0 at k=41 -> multiplies bias row
#pragma unroll
        for (int i = 2; i < 8; ++i) a1[i] = 0;
      } else {
#pragma unroll
        for (int i = 0; i < 8; ++i) a1[i] = 0;
      }
      Ae0[ti] = a0;
      Ae1[ti] = a1;
      // write-through for layers 2-3 (layout == old eprep output)
      unsigned short* op = Eimg + (size_t)er * EROW;
      *(bf8*)(op + quad * 8) = a0;
      if (quad < 2) *(bf8*)(op + 32 + quad * 8) = a1;
    }
  }

  // ---- early X loads for the tail ----
  float xpre[2];
#pragma unroll
  for (int al = 0; al < 2; ++al)
    xpre[al] = X[(size_t)(g * GA + wv * 2 + al) * 64 + lane];

  // ---- MFMA: ct outer (Wi fragments loaded once), ti inner ----
  const f32x4 z = {0.f, 0.f, 0.f, 0.f};
#pragma unroll 1
  for (int ct = 0; ct < 8; ++ct) {
    const unsigned short* wp = Wi + ct * 1024 + lane * 8;
    const bf8 Be0 = *(const bf8*)(wp);
    const bf8 Be1 = *(const bf8*)(wp + 512);
    const bf8 Bs0 = *(const bf8*)(wp + 8192);
    const bf8 Bs1 = *(const bf8*)(wp + 8192 + 512);
    const bf8 Bn0 = *(const bf8*)(wp + 16384);
    const bf8 Bn1 = *(const bf8*)(wp + 16384 + 512);
#pragma unroll
    for (int ti = 0; ti < 2; ++ti) {
      if (ti < ntile) {
        const int rbase = (wv + ti * 4) * 16;
        f32x4 acc = MFMA_B16(Ax0[ti], Bn0, z);
        acc = MFMA_B16(Ax1[ti], Bn1, acc);
        acc = MFMA_B16(As0[ti], Bs0, acc);
        acc = MFMA_B16(As1[ti], Bs1, acc);
        acc = MFMA_B16(Ae0[ti], Be0, acc);
        acc = MFMA_B16(Ae1[ti], Be1, acc);
        const int j = ct * 16 + l15;
        const int c = j >> 1, h = j & 1;
#pragma unroll
        for (int r = 0; r < 4; r += 2) {
          const unsigned int pk = pkbf(acc[r], acc[r + 1]);
          const int row0 = rbase + quad * 4 + r;
          const int row1 = row0 + 1;
          eb16[row0 * 128 + ((c + row0) & 63) * 2 + h] = (unsigned short)pk;
          eb16[row1 * 128 + ((c + row1) & 63) * 2 + h] =
              (unsigned short)(pk >> 16);
        }
      }
    }
  }
  __syncthreads();

  // ---- tail ----
  const float inv = rsqrtf(1.f + EPSBN);
  const float s2 = g2[lane] * inv, o2 = b2[lane];
#pragma unroll
  for (int al = 0; al < 2; ++al) {
    const int a_local = wv * 2 + al;
    const int n = g * GA + a_local;
    float acc = 0.f;
#pragma unroll
    for (int m = 0; m < 12; ++m) {
      const int row = a_local * 12 + m;
      const uint32_t eu = eb32[row * 64 + ((lane + row) & 63)];
      acc += sig(lo16(eu)) * sp(hi16(eu));
    }
    const size_t o = (size_t)n * 64 + lane;
    const float res = sp(xpre[al] + acc * s2 + o2);
    X[o] = res;
    const unsigned int u = (unsigned short)f2bf(res);
    const unsigned int p = __shfl_xor((int)u, 1);
    if (!(lane & 1)) XbOutU[(size_t)n * 32 + (lane >> 1)] = u | (p << 16);
  }
}

// ---------------------------------------------------------------------------
// FUSED conv layers 2-3, FAST PATH: R10 structure + pk-pair epilogue.
// ---------------------------------------------------------------------------
__global__ __launch_bounds__(256, 5) void k_fused6(
    float* __restrict__ X, const unsigned short* __restrict__ XbIn,
    unsigned int* __restrict__ XbOutU, const unsigned short* __restrict__ Eimg,
    const int* __restrict__ IDX, const unsigned short* __restrict__ Wi,
    const float* __restrict__ g2, const float* __restrict__ b2) {
  __shared__ __align__(16) unsigned int eb32[ROWS * 64];  // 24576 B
  unsigned short* eb16 = (unsigned short*)eb32;
  const int tid = threadIdx.x;
  const int lane = tid & 63, wv = tid >> 6;
  const int quad = lane >> 4, l15 = lane & 15;
  const int g = blockIdx.x;
  const int ntile = (wv < 2) ? 2 : 1;  // 6 row-tiles over 4 waves

  bf8 Ax0[2], Ax1[2], As0[2], As1[2], Ae0[2], Ae1[2];
#pragma unroll
  for (int ti = 0; ti < 2; ++ti) {
    if (ti < ntile) {
      const int rbase = (wv + ti * 4) * 16;
      const int er = g * ROWS + rbase + l15;
      const int jr = IDX[er];
      const unsigned short* xr = XbIn + (size_t)jr * 64 + quad * 8;
      Ax0[ti] = *(const bf8*)xr;
      Ax1[ti] = *(const bf8*)(xr + 32);
      const int arow = g * GA + (rbase + l15) / M_NBR;
      const unsigned short* sr = XbIn + (size_t)arow * 64 + quad * 8;
      As0[ti] = *(const bf8*)sr;
      As1[ti] = *(const bf8*)(sr + 32);
      const unsigned short* ep = Eimg + (size_t)er * EROW;
      Ae0[ti] = *(const bf8*)(ep + quad * 8);
      bf8 a1;
#pragma unroll
      for (int i = 0; i < 8; ++i) a1[i] = 0;
      if (quad < 2) a1 = *(const bf8*)(ep + 32 + quad * 8);
      Ae1[ti] = a1;
    }
  }

  float xpre[2];
#pragma unroll
  for (int al = 0; al < 2; ++al)
    xpre[al] = X[(size_t)(g * GA + wv * 2 + al) * 64 + lane];

  const f32x4 z = {0.f, 0.f, 0.f, 0.f};
#pragma unroll 1
  for (int ct = 0; ct < 8; ++ct) {
    const unsigned short* wp = Wi + ct * 1024 + lane * 8;
    const bf8 Be0 = *(const bf8*)(wp);
    const bf8 Be1 = *(const bf8*)(wp + 512);
    const bf8 Bs0 = *(const bf8*)(wp + 8192);
    const bf8 Bs1 = *(const bf8*)(wp + 8192 + 512);
    const bf8 Bn0 = *(const bf8*)(wp + 16384);
    const bf8 Bn1 = *(const bf8*)(wp + 16384 + 512);
#pragma unroll
    for (int ti = 0; ti < 2; ++ti) {
      if (ti < ntile) {
        const int rbase = (wv + ti * 4) * 16;
        f32x4 acc = MFMA_B16(Ax0[ti], Bn0, z);
        acc = MFMA_B16(Ax1[ti], Bn1, acc);
        acc = MFMA_B16(As0[ti], Bs0, acc);
        acc = MFMA_B16(As1[ti], Bs1, acc);
        acc = MFMA_B16(Ae0[ti], Be0, acc);
        acc = MFMA_B16(Ae1[ti], Be1, acc);
        const int j = ct * 16 + l15;
        const int c = j >> 1, h = j & 1;
#pragma unroll
        for (int r = 0; r < 4; r += 2) {
          const unsigned int pk = pkbf(acc[r], acc[r + 1]);
          const int row0 = rbase + quad * 4 + r;
          const int row1 = row0 + 1;
          eb16[row0 * 128 + ((c + row0) & 63) * 2 + h] = (unsigned short)pk;
          eb16[row1 * 128 + ((c + row1) & 63) * 2 + h] =
              (unsigned short)(pk >> 16);
        }
      }
    }
  }
  __syncthreads();

  const float inv = rsqrtf(1.f + EPSBN);
  const float s2 = g2[lane] * inv, o2 = b2[lane];
#pragma unroll
  for (int al = 0; al < 2; ++al) {
    const int a_local = wv * 2 + al;
    const int n = g * GA + a_local;
    float acc = 0.f;
#pragma unroll
    for (int m = 0; m < 12; ++m) {
      const int row = a_local * 12 + m;
      const uint32_t eu = eb32[row * 64 + ((lane + row) & 63)];
      acc += sig(lo16(eu)) * sp(hi16(eu));
    }
    const size_t o = (size_t)n * 64 + lane;
    const float res = sp(xpre[al] + acc * s2 + o2);
    X[o] = res;
    const unsigned int u = (unsigned short)f2bf(res);
    const unsigned int p = __shfl_xor((int)u, 1);
    if (!(lane & 1)) XbOutU[(size_t)n * 32 + (lane >> 1)] = u | (p << 16);
  }
}

// ---------------------------------------------------------------------------
// FUSED conv layer, FALLBACK: verbatim R0 kernel (proven 567 us config).
// ---------------------------------------------------------------------------
__global__ __launch_bounds__(256, 5) void k_fused4(
    float* __restrict__ X, const unsigned short* __restrict__ XbIn,
    unsigned int* __restrict__ XbOutU, const float* __restrict__ NF,
    const int* __restrict__ IDX, const unsigned short* __restrict__ Wi,
    const float* __restrict__ g2, const float* __restrict__ b2) {
  __shared__ __align__(16) unsigned int eb32[ROWS * 64];  // 24576 B
  unsigned short* eb16 = (unsigned short*)eb32;
  float* stage = (float*)eb32;  // first 3936 floats = 96x41 tile
  const int tid = threadIdx.x;
  const int lane = tid & 63, wv = tid >> 6;
  const int quad = lane >> 4, l15 = lane & 15;
  const int g = blockIdx.x;
  const int ntile = (wv < 2) ? 2 : 1;  // 6 row-tiles over 4 waves

  bf8 Ax0[2], Ax1[2], As0[2], As1[2];
#pragma unroll
  for (int ti = 0; ti < 2; ++ti) {
    if (ti < ntile) {
      const int rbase = (wv + ti * 4) * 16;
      const int jr = IDX[g * ROWS + rbase + l15];
      const unsigned short* xr = XbIn + (size_t)jr * 64 + quad * 8;
      Ax0[ti] = *(const bf8*)xr;
      Ax1[ti] = *(const bf8*)(xr + 32);
      const int arow = g * GA + (rbase + l15) / M_NBR;
      const unsigned short* sr = XbIn + (size_t)arow * 64 + quad * 8;
      As0[ti] = *(const bf8*)sr;
      As1[ti] = *(const bf8*)(sr + 32);
    }
  }

  const float4* s4 = (const float4*)(NF + (size_t)g * (ROWS * NBF));
#pragma unroll
  for (int it = 0; it < 4; ++it) {
    const int w = tid + it * 256;
    if (w < (ROWS * NBF) / 4) ((float4*)stage)[w] = s4[w];
  }
  __syncthreads();

  bf8 Ae0[2], Ae1[2];
#pragma unroll
  for (int ti = 0; ti < 2; ++ti) {
    if (ti < ntile) {
      const int rbase = (wv + ti * 4) * 16;
      const float* rp = stage + (rbase + l15) * NBF;
      bf8 a0, a1;
#pragma unroll
      for (int i = 0; i < 8; ++i) a0[i] = f2bf(rp[quad * 8 + i]);
      if (quad == 0) {
#pragma unroll
        for (int i = 0; i < 8; ++i) a1[i] = f2bf(rp[32 + i]);
      } else if (quad == 1) {
        a1[0] = f2bf(rp[40]);
        a1[1] = (short)0x3F80;  // bf16 1.0 at k=41 -> multiplies bias row
#pragma unroll
        for (int i = 2; i < 8; ++i) a1[i] = 0;
      } else {
#pragma unroll
        for (int i = 0; i < 8; ++i) a1[i] = 0;
      }
      Ae0[ti] = a0;
      Ae1[ti] = a1;
    }
  }
  __syncthreads();

#pragma unroll
  for (int ti = 0; ti < 2; ++ti) {
    if (ti < ntile) {
      const int rbase = (wv + ti * 4) * 16;
      const f32x4 z = {0.f, 0.f, 0.f, 0.f};
#pragma unroll 1
      for (int ct = 0; ct < 8; ++ct) {
        const bf8 Be0 = *(const bf8*)(Wi + ((ct * 2 + 0) * 64 + lane) * 8);
        const bf8 Be1 = *(const bf8*)(Wi + ((ct * 2 + 1) * 64 + lane) * 8);
        const bf8 Bs0 =
            *(const bf8*)(Wi + 8192 + ((ct * 2 + 0) * 64 + lane) * 8);
        const bf8 Bs1 =
            *(const bf8*)(Wi + 8192 + ((ct * 2 + 1) * 64 + lane) * 8);
        const bf8 Bn0 =
            *(const bf8*)(Wi + 16384 + ((ct * 2 + 0) * 64 + lane) * 8);
        const bf8 Bn1 =
            *(const bf8*)(Wi + 16384 + ((ct * 2 + 1) * 64 + lane) * 8);
        f32x4 acc = MFMA_B16(Ax0[ti], Bn0, z);
        acc = MFMA_B16(Ax1[ti], Bn1, acc);
        acc = MFMA_B16(As0[ti], Bs0, acc);
        acc = MFMA_B16(As1[ti], Bs1, acc);
        acc = MFMA_B16(Ae0[ti], Be0, acc);
        acc = MFMA_B16(Ae1[ti], Be1, acc);
        const int j = ct * 16 + l15;
        const int c = j >> 1, h = j & 1;
#pragma unroll
        for (int r = 0; r < 4; ++r) {
          const int row = rbase + quad * 4 + r;
          eb16[row * 128 + ((c + row) & 63) * 2 + h] =
              (unsigned short)f2bf(acc[r]);
        }
      }
    }
  }
  __syncthreads();

  const float inv = rsqrtf(1.f + EPSBN);
  const float s2 = g2[lane] * inv, o2 = b2[lane];
#pragma unroll
  for (int al = 0; al < 2; ++al) {
    const int a_local = wv * 2 + al;
    const int n = g * GA + a_local;
    float acc = 0.f;
#pragma unroll
    for (int m = 0; m < 12; ++m) {
      const int row = a_local * 12 + m;
      const uint32_t eu = eb32[row * 64 + ((lane + row) & 63)];
      acc += sig(lo16(eu)) * sp(hi16(eu));
    }
    const size_t o = (size_t)n * 64 + lane;
    const float res = sp(X[o] + acc * s2 + o2);
    X[o] = res;
    const unsigned int u = (unsigned short)f2bf(res);
    const unsigned int p = __shfl_xor((int)u, 1);
    if (!(lane & 1)) XbOutU[(size_t)n * 32 + (lane >> 1)] = u | (p << 16);
  }
}

// ---------------------------------------------------------------------------
// Head: pooling with precomputed bounds, 256 threads (verbatim R8).
// ---------------------------------------------------------------------------
__global__ __launch_bounds__(256) void k_head(
    const float* __restrict__ Xf, const int* __restrict__ bounds,
    const float* __restrict__ EF, const float* __restrict__ Wx,
    const float* __restrict__ bx, const float* __restrict__ gx,
    const float* __restrict__ bxb, const float* __restrict__ Wfc,
    const float* __restrict__ bfc, const float* __restrict__ Wo0,
    const float* __restrict__ bo0, const float* __restrict__ Wo1,
    const float* __restrict__ bo1, const float* __restrict__ Wo2,
    const float* __restrict__ bo2, float* __restrict__ out) {
  const int b = blockIdx.x;
  const int t = threadIdx.x;
  __shared__ float vbuf[80];
  __shared__ float part[256];
  __shared__ float4 r4[128];
  const int lo = bounds[b];
  const int hi = bounds[b + 1];
  const int col = t & 63, qq = t >> 6;  // 4-way over rows
  float s = 0.f;
  for (int r = lo + qq; r < hi; r += 4) s += Xf[(size_t)r * 64 + col];
  part[t] = s;
  __syncthreads();
  if (t < 64) {
    vbuf[t] = (part[t] + part[t + 64] + part[t + 128] + part[t + 192]) /
              fmaxf((float)(hi - lo), 1.f);
  } else if (t < 80) {
    const int e = t - 64;
    float a = bx[e];
#pragma unroll
    for (int k = 0; k < 8; ++k) a += EF[b * 8 + k] * Wx[k * 16 + e];
    a = a * (gx[e] * rsqrtf(1.f + EPSBN)) + bxb[e];
    vbuf[t] = sp(a);
  }
  __syncthreads();
  if (t < 128) {
    float h = bfc[t];
#pragma unroll
    for (int k = 0; k < 80; ++k) h += vbuf[k] * Wfc[k * 128 + t];
    h = sp(h);
    r4[t] = make_float4(h * Wo0[t], h * Wo1[2 * t], h * Wo1[2 * t + 1],
                        h * Wo2[t]);
  }
  __syncthreads();
  for (int st2 = 64; st2 > 0; st2 >>= 1) {
    if (t < st2) {
      float4 a = r4[t], c = r4[t + st2];
      r4[t] = make_float4(a.x + c.x, a.y + c.y, a.z + c.z, a.w + c.w);
    }
    __syncthreads();
  }
  if (t == 0) {
    float4 r = r4[0];
    out[b] = r.x + bo0[0];
    float z0 = r.y + bo1[0], z1 = r.z + bo1[1];
    float mx = fmaxf(z0, z1);
    float lse = mx + __logf(__expf(z0 - mx) + __expf(z1 - mx));
    out[B_CRYS + 2 * b] = z0 - lse;
    out[B_CRYS + 2 * b + 1] = z1 - lse;
    out[3 * B_CRYS + b] = r.w + bo2[0];
  }
}

// ---------------------------------------------------------------------------
extern "C" void kernel_launch(void* const* d_in, const int* in_sizes, int n_in,
                              void* d_out, int out_size, void* d_ws,
                              size_t ws_size, hipStream_t stream) {
  const float* atom_fea = (const float*)d_in[0];
  const float* nbr_fea  = (const float*)d_in[1];
  const int*   nbr_idx  = (const int*)d_in[2];
  const int*   seg      = (const int*)d_in[3];
  const float* extra    = (const float*)d_in[4];
  const float* W_embed  = (const float*)d_in[5];
  const float* b_embed  = (const float*)d_in[6];
  const float* conv_W   = (const float*)d_in[7];
  const float* conv_b   = (const float*)d_in[8];
  const float* bn1_g    = (const float*)d_in[9];
  const float* bn1_b    = (const float*)d_in[10];
  const float* bn2_g    = (const float*)d_in[11];
  const float* bn2_b    = (const float*)d_in[12];
  const float* W_extra  = (const float*)d_in[13];
  const float* b_extra  = (const float*)d_in[14];
  const float* bnx_g    = (const float*)d_in[15];
  const float* bnx_b    = (const float*)d_in[16];
  const float* W_fc     = (const float*)d_in[17];
  const float* b_fc     = (const float*)d_in[18];
  const float* W_out0   = (const float*)d_in[19];
  const float* b_out0   = (const float*)d_in[20];
  const float* W_out1   = (const float*)d_in[21];
  const float* b_out1   = (const float*)d_in[22];
  const float* W_out2   = (const float*)d_in[23];
  const float* b_out2   = (const float*)d_in[24];
  float* out = (float*)d_out;

  // ws layout: X f32 | XbU0 | XbU1 | Wimg | bounds | [Eimg if it fits]
  float* x = (float*)d_ws;
  unsigned int* xbu0 = (unsigned int*)(x + (size_t)N_ATOMS * 64);
  unsigned int* xbu1 = xbu0 + (size_t)N_ATOMS * 32;
  unsigned short* Wimg = (unsigned short*)(xbu1 + (size_t)N_ATOMS * 32);
  int* bounds = (int*)(Wimg + (size_t)3 * WIMG_L);
  unsigned short* Eimg = (unsigned short*)(bounds + 2052);  // 16B-aligned

  const size_t base_bytes =
      (size_t)N_ATOMS * 64 * 4 + (size_t)N_ATOMS * 32 * 4 * 2 +
      (size_t)3 * WIMG_L * 2 + 2052 * 4;
  const size_t eimg_bytes = (size_t)EP_ROWS * EROW * 2;  // 69.12 MB
  const bool use_eimg = (ws_size >= base_bytes + eimg_bytes);

  hipLaunchKernelGGL(k_pre, dim3(PRE_GRID), dim3(256), 0, stream, conv_W,
                     conv_b, bn1_g, bn1_b, Wimg, atom_fea, W_embed, b_embed, x,
                     xbu0, seg, bounds);

  unsigned int* xin = xbu0;
  unsigned int* xout = xbu1;
  for (int i = 0; i < 3; ++i) {
    if (use_eimg) {
      if (i == 0) {
        hipLaunchKernelGGL(k_fused7, dim3(GRID_F), dim3(256), 0, stream, x,
                           (const unsigned short*)xin, xout, nbr_fea, Eimg,
                           nbr_idx, Wimg + (size_t)i * WIMG_L, bn2_g + i * 64,
                           bn2_b + i * 64);
      } else {
        hipLaunchKernelGGL(k_fused6, dim3(GRID_F), dim3(256), 0, stream, x,
                           (const unsigned short*)xin, xout, Eimg, nbr_idx,
                           Wimg + (size_t)i * WIMG_L, bn2_g + i * 64,
                           bn2_b + i * 64);
      }
    } else {
      hipLaunchKernelGGL(k_fused4, dim3(GRID_F), dim3(256), 0, stream, x,
                         (const unsigned short*)xin, xout, nbr_fea, nbr_idx,
                         Wimg + (size_t)i * WIMG_L, bn2_g + i * 64,
                         bn2_b + i * 64);
    }
    unsigned int* tmp = xin;
    xin = xout;
    xout = tmp;
  }
  hipLaunchKernelGGL(k_head, dim3(B_CRYS), dim3(256), 0, stream, x, bounds,
                     extra, W_extra, b_extra, bnx_g, bnx_b, W_fc, b_fc, W_out0,
                     b_out0, W_out1, b_out1, W_out2, b_out2, out);
}

// Round 14
// 487.040 us; speedup vs baseline: 1.6662x; 1.0396x over previous
//
#include <hip/hip_runtime.h>
#include <math.h>
#include <stdint.h>

#define N_ATOMS 60000
#define M_NBR   12
#define NBF     41
#define B_CRYS  2048
#define EPSBN   1e-5f
// fallback geometry (k_fused4, proven R0)
#define GA      8
#define ROWS    (GA * M_NBR)      // 96
#define GRID_F  (N_ATOMS / GA)    // 7500
// fast-path geometry: 16 atoms/block -> 12 row-tiles over 4 waves = 3 each
#define GAF     16
#define ROWSF   (GAF * M_NBR)     // 192
#define GRIDF   (N_ATOMS / GAF)   // 3750
#define WIMG_L  24576             // shorts per layer: [edge][self][nbr] x 8192
#define EROW    48                // shorts per edge row in Eimg (41 + bias + pad)
#define EP_ROWS (N_ATOMS * M_NBR) // 720000 edge rows total

// k_pre block partition: [0,288) wprep | [288,1248) embed | [1248,1257) bounds
#define PRE_WP   288
#define PRE_EMB  960
#define PRE_B    9
#define PRE_GRID (PRE_WP + PRE_EMB + PRE_B)

typedef __attribute__((ext_vector_type(8))) short bf8;
typedef __attribute__((ext_vector_type(4))) float f32x4;
#define MFMA_B16(a, b, c) __builtin_amdgcn_mfma_f32_16x16x32_bf16(a, b, c, 0, 0, 0)

__device__ __forceinline__ short f2bf(float f) {
  uint32_t u = __builtin_bit_cast(uint32_t, f);
  u += 0x7FFFu + ((u >> 16) & 1u);
  return (short)(u >> 16);
}
__device__ __forceinline__ float lo16(uint32_t u) {
  return __builtin_bit_cast(float, u << 16);
}
__device__ __forceinline__ float hi16(uint32_t u) {
  return __builtin_bit_cast(float, u & 0xFFFF0000u);
}
__device__ __forceinline__ float sp(float x) {
  return (x > 15.f) ? x : __logf(1.f + __expf(x));
}
__device__ __forceinline__ float sig(float x) {
  return 1.f / (1.f + __expf(-x));
}
__device__ __forceinline__ int lbound(const int* __restrict__ a, int n, int v) {
  int lo = 0, hi = n;
  while (lo < hi) {
    int mid = (lo + hi) >> 1;
    if (a[mid] < v) lo = mid + 1; else hi = mid;
  }
  return lo;
}

// ---------------------------------------------------------------------------
// MERGED PREP: wprep + embed2 + segment-bounds (verbatim R10, legacy map).
// ---------------------------------------------------------------------------
__global__ __launch_bounds__(256) void k_pre(
    const float* __restrict__ conv_W, const float* __restrict__ conv_b,
    const float* __restrict__ bn1_g, const float* __restrict__ bn1_b,
    unsigned short* __restrict__ Wimg, const float* __restrict__ A,
    const float* __restrict__ W, const float* __restrict__ bias,
    float* __restrict__ X, unsigned int* __restrict__ XbU,
    const int* __restrict__ seg, int* __restrict__ bounds) {
  const int b = blockIdx.x;

  if (b < PRE_WP) {
    // ---------------- wprep ----------------
    const int gid = b * 256 + threadIdx.x;
    if (gid >= 3 * WIMG_L) return;
    const int layer = gid / WIMG_L, rem = gid % WIMG_L;
    const int which = rem / 8192, r2 = rem % 8192;
    const int frag = r2 >> 9, lane = (r2 >> 3) & 63, j = r2 & 7;
    const int ct = frag >> 1, ks = frag & 1;
    const int quad = lane >> 4, l15 = lane & 15;
    const int jc = ct * 16 + l15;
    const int oc = (jc & 1) ? (jc >> 1) + 64 : (jc >> 1);
    const float s = bn1_g[layer * 128 + oc] * rsqrtf(1.f + EPSBN);
    const int k = ks * 32 + quad * 8 + j;
    const float* Wc = conv_W + (size_t)layer * 169 * 128;
    float v = 0.f;
    if (which == 0) {
      if (k < NBF) v = Wc[(128 + k) * 128 + oc] * s;
      else if (k == NBF)
        v = conv_b[layer * 128 + oc] * s + bn1_b[layer * 128 + oc];
    } else if (which == 1) {
      v = Wc[k * 128 + oc] * s;
    } else {
      v = Wc[(64 + k) * 128 + oc] * s;
    }
    Wimg[gid] = (unsigned short)f2bf(v);
    return;
  }

  if (b < PRE_WP + PRE_EMB) {
    // ---------------- embed2 ----------------
    const int lane = threadIdx.x & 63, wv = threadIdx.x >> 6;
    const int quad = lane >> 4, l15 = lane & 15;
    const int gw = (b - PRE_WP) * 4 + wv;
    const int nw = PRE_EMB * 4;
    bf8 Bf[3][4];
    float bs[4];
#pragma unroll
    for (int ct = 0; ct < 4; ++ct) {
      const int col = ct * 16 + l15;
      bs[ct] = bias[col];
#pragma unroll
      for (int ks = 0; ks < 3; ++ks) {
        bf8 bb;
#pragma unroll
        for (int i = 0; i < 8; ++i) {
          const int k = ks * 32 + quad * 8 + i;
          bb[i] = (k < 92) ? f2bf(W[k * 64 + col]) : (short)0;
        }
        Bf[ks][ct] = bb;
      }
    }
    for (int rt = gw; rt < 3750; rt += nw) {
      const int rbase = rt * 16;
      const float* ar = A + (size_t)(rbase + l15) * 92;
      const float4 p0 = *(const float4*)(ar + quad * 8);
      const float4 p1 = *(const float4*)(ar + quad * 8 + 4);
      const float4 p2 = *(const float4*)(ar + 32 + quad * 8);
      const float4 p3 = *(const float4*)(ar + 32 + quad * 8 + 4);
      bf8 A0, A1, A2;
      A0[0] = f2bf(p0.x); A0[1] = f2bf(p0.y); A0[2] = f2bf(p0.z); A0[3] = f2bf(p0.w);
      A0[4] = f2bf(p1.x); A0[5] = f2bf(p1.y); A0[6] = f2bf(p1.z); A0[7] = f2bf(p1.w);
      A1[0] = f2bf(p2.x); A1[1] = f2bf(p2.y); A1[2] = f2bf(p2.z); A1[3] = f2bf(p2.w);
      A1[4] = f2bf(p3.x); A1[5] = f2bf(p3.y); A1[6] = f2bf(p3.z); A1[7] = f2bf(p3.w);
#pragma unroll
      for (int i = 0; i < 8; ++i) {
        const int k = 64 + quad * 8 + i;
        A2[i] = (k < 92) ? f2bf(ar[k]) : (short)0;
      }
      const f32x4 z = {0.f, 0.f, 0.f, 0.f};
      f32x4 acc[4];
#pragma unroll
      for (int ct = 0; ct < 4; ++ct) {
        acc[ct] = MFMA_B16(A0, Bf[0][ct], z);
        acc[ct] = MFMA_B16(A1, Bf[1][ct], acc[ct]);
        acc[ct] = MFMA_B16(A2, Bf[2][ct], acc[ct]);
      }
#pragma unroll
      for (int ct = 0; ct < 4; ++ct)
#pragma unroll
        for (int r = 0; r < 4; ++r) {
          const int row = rbase + quad * 4 + r;
          const float v = acc[ct][r] + bs[ct];
          X[(size_t)row * 64 + ct * 16 + l15] = v;
          const unsigned int u = (unsigned short)f2bf(v);
          const unsigned int p = __shfl_xor((int)u, 1);
          if (!(l15 & 1))
            XbU[(size_t)row * 32 + ct * 8 + (l15 >> 1)] = u | (p << 16);
        }
    }
    return;
  }

  // ---------------- bounds: bounds[b] = lbound(seg, b), b in [0,2048] ------
  const int bi = (b - PRE_WP - PRE_EMB) * 256 + threadIdx.x;
  if (bi <= B_CRYS) bounds[bi] = lbound(seg, N_ATOMS, bi);
}

// ---------------------------------------------------------------------------
// FUSED conv LAYER 1 (fast path, GA=16): 12 row-tiles over 4 waves = 3 each
// (perfect balance; old GA=8 left waves 2-3 idle half the MFMA phase). Edge
// A-fragments from f32 NF with bf16 write-through to Eimg. ct-outer Wi reuse
// now amortized over 3 tiles. launch_bounds(256,3): 3 blocks/CU (LDS 48KB),
// VGPR budget ~170 so the 18 A-fragments do NOT spill (R12 lesson).
// ---------------------------------------------------------------------------
__global__ __launch_bounds__(256, 3) void k_fused7(
    float* __restrict__ X, const unsigned short* __restrict__ XbIn,
    unsigned int* __restrict__ XbOutU, const float* __restrict__ NF,
    unsigned short* __restrict__ Eimg, const int* __restrict__ IDX,
    const unsigned short* __restrict__ Wi, const float* __restrict__ g2,
    const float* __restrict__ b2) {
  __shared__ __align__(16) unsigned int eb32[ROWSF * 64];  // 49152 B
  unsigned short* eb16 = (unsigned short*)eb32;
  const int tid = threadIdx.x;
  const int lane = tid & 63, wv = tid >> 6;
  const int quad = lane >> 4, l15 = lane & 15;
  const int g = blockIdx.x;

  // ---- neighbor/self gathers + edge from NF (+ Eimg write-through) ----
  bf8 Ax0[3], Ax1[3], As0[3], As1[3], Ae0[3], Ae1[3];
#pragma unroll
  for (int ti = 0; ti < 3; ++ti) {
    const int rbase = (wv + ti * 4) * 16;
    const int er = g * ROWSF + rbase + l15;
    const int jr = IDX[er];
    const unsigned short* xr = XbIn + (size_t)jr * 64 + quad * 8;
    Ax0[ti] = *(const bf8*)xr;
    Ax1[ti] = *(const bf8*)(xr + 32);
    const int arow = g * GAF + (rbase + l15) / M_NBR;
    const unsigned short* sr = XbIn + (size_t)arow * 64 + quad * 8;
    As0[ti] = *(const bf8*)sr;
    As1[ti] = *(const bf8*)(sr + 32);

    const float* rp = NF + (size_t)er * NBF;
    bf8 a0, a1;
    const float4 q0 = *(const float4*)(rp + quad * 8);
    const float4 q1 = *(const float4*)(rp + quad * 8 + 4);
    a0[0] = f2bf(q0.x); a0[1] = f2bf(q0.y); a0[2] = f2bf(q0.z); a0[3] = f2bf(q0.w);
    a0[4] = f2bf(q1.x); a0[5] = f2bf(q1.y); a0[6] = f2bf(q1.z); a0[7] = f2bf(q1.w);
    if (quad == 0) {
      const float4 q2 = *(const float4*)(rp + 32);
      const float4 q3 = *(const float4*)(rp + 36);
      a1[0] = f2bf(q2.x); a1[1] = f2bf(q2.y); a1[2] = f2bf(q2.z); a1[3] = f2bf(q2.w);
      a1[4] = f2bf(q3.x); a1[5] = f2bf(q3.y); a1[6] = f2bf(q3.z); a1[7] = f2bf(q3.w);
    } else if (quad == 1) {
      a1[0] = f2bf(rp[40]);     // scalar: no overrun on last row
      a1[1] = (short)0x3F80;    // bf16 1.0 at k=41 -> multiplies bias row
#pragma unroll
      for (int i = 2; i < 8; ++i) a1[i] = 0;
    } else {
#pragma unroll
      for (int i = 0; i < 8; ++i) a1[i] = 0;
    }
    Ae0[ti] = a0;
    Ae1[ti] = a1;
    // write-through for layers 2-3 (layout == old eprep output)
    unsigned short* op = Eimg + (size_t)er * EROW;
    *(bf8*)(op + quad * 8) = a0;
    if (quad < 2) *(bf8*)(op + 32 + quad * 8) = a1;
  }

  // ---- early X loads for the tail ----
  float xpre[4];
#pragma unroll
  for (int al = 0; al < 4; ++al)
    xpre[al] = X[(size_t)(g * GAF + wv * 4 + al) * 64 + lane];

  // ---- MFMA: ct outer (Wi fragments loaded once, reused x3 tiles) ----
  const f32x4 z = {0.f, 0.f, 0.f, 0.f};
#pragma unroll 1
  for (int ct = 0; ct < 8; ++ct) {
    const unsigned short* wp = Wi + ct * 1024 + lane * 8;
    const bf8 Be0 = *(const bf8*)(wp);
    const bf8 Be1 = *(const bf8*)(wp + 512);
    const bf8 Bs0 = *(const bf8*)(wp + 8192);
    const bf8 Bs1 = *(const bf8*)(wp + 8192 + 512);
    const bf8 Bn0 = *(const bf8*)(wp + 16384);
    const bf8 Bn1 = *(const bf8*)(wp + 16384 + 512);
#pragma unroll
    for (int ti = 0; ti < 3; ++ti) {
      const int rbase = (wv + ti * 4) * 16;
      f32x4 acc = MFMA_B16(Ax0[ti], Bn0, z);
      acc = MFMA_B16(Ax1[ti], Bn1, acc);
      acc = MFMA_B16(As0[ti], Bs0, acc);
      acc = MFMA_B16(As1[ti], Bs1, acc);
      acc = MFMA_B16(Ae0[ti], Be0, acc);
      acc = MFMA_B16(Ae1[ti], Be1, acc);
      const int j = ct * 16 + l15;
      const int c = j >> 1, h = j & 1;
#pragma unroll
      for (int r = 0; r < 4; ++r) {
        const int row = rbase + quad * 4 + r;
        eb16[row * 128 + ((c + row) & 63) * 2 + h] =
            (unsigned short)f2bf(acc[r]);
      }
    }
  }
  __syncthreads();

  // ---- tail: 4 atoms per wave ----
  const float inv = rsqrtf(1.f + EPSBN);
  const float s2 = g2[lane] * inv, o2 = b2[lane];
#pragma unroll
  for (int al = 0; al < 4; ++al) {
    const int a_local = wv * 4 + al;
    const int n = g * GAF + a_local;
    float acc = 0.f;
#pragma unroll
    for (int m = 0; m < 12; ++m) {
      const int row = a_local * 12 + m;
      const uint32_t eu = eb32[row * 64 + ((lane + row) & 63)];
      acc += sig(lo16(eu)) * sp(hi16(eu));
    }
    const size_t o = (size_t)n * 64 + lane;
    const float res = sp(xpre[al] + acc * s2 + o2);
    X[o] = res;
    const unsigned int u = (unsigned short)f2bf(res);
    const unsigned int p = __shfl_xor((int)u, 1);
    if (!(lane & 1)) XbOutU[(size_t)n * 32 + (lane >> 1)] = u | (p << 16);
  }
}

// ---------------------------------------------------------------------------
// FUSED conv layers 2-3, FAST PATH (GA=16, balanced): edge from Eimg.
// ---------------------------------------------------------------------------
__global__ __launch_bounds__(256, 3) void k_fused6(
    float* __restrict__ X, const unsigned short* __restrict__ XbIn,
    unsigned int* __restrict__ XbOutU, const unsigned short* __restrict__ Eimg,
    const int* __restrict__ IDX, const unsigned short* __restrict__ Wi,
    const float* __restrict__ g2, const float* __restrict__ b2) {
  __shared__ __align__(16) unsigned int eb32[ROWSF * 64];  // 49152 B
  unsigned short* eb16 = (unsigned short*)eb32;
  const int tid = threadIdx.x;
  const int lane = tid & 63, wv = tid >> 6;
  const int quad = lane >> 4, l15 = lane & 15;
  const int g = blockIdx.x;

  bf8 Ax0[3], Ax1[3], As0[3], As1[3], Ae0[3], Ae1[3];
#pragma unroll
  for (int ti = 0; ti < 3; ++ti) {
    const int rbase = (wv + ti * 4) * 16;
    const int er = g * ROWSF + rbase + l15;
    const int jr = IDX[er];
    const unsigned short* xr = XbIn + (size_t)jr * 64 + quad * 8;
    Ax0[ti] = *(const bf8*)xr;
    Ax1[ti] = *(const bf8*)(xr + 32);
    const int arow = g * GAF + (rbase + l15) / M_NBR;
    const unsigned short* sr = XbIn + (size_t)arow * 64 + quad * 8;
    As0[ti] = *(const bf8*)sr;
    As1[ti] = *(const bf8*)(sr + 32);
    const unsigned short* ep = Eimg + (size_t)er * EROW;
    Ae0[ti] = *(const bf8*)(ep + quad * 8);
    bf8 a1;
#pragma unroll
    for (int i = 0; i < 8; ++i) a1[i] = 0;
    if (quad < 2) a1 = *(const bf8*)(ep + 32 + quad * 8);
    Ae1[ti] = a1;
  }

  float xpre[4];
#pragma unroll
  for (int al = 0; al < 4; ++al)
    xpre[al] = X[(size_t)(g * GAF + wv * 4 + al) * 64 + lane];

  const f32x4 z = {0.f, 0.f, 0.f, 0.f};
#pragma unroll 1
  for (int ct = 0; ct < 8; ++ct) {
    const unsigned short* wp = Wi + ct * 1024 + lane * 8;
    const bf8 Be0 = *(const bf8*)(wp);
    const bf8 Be1 = *(const bf8*)(wp + 512);
    const bf8 Bs0 = *(const bf8*)(wp + 8192);
    const bf8 Bs1 = *(const bf8*)(wp + 8192 + 512);
    const bf8 Bn0 = *(const bf8*)(wp + 16384);
    const bf8 Bn1 = *(const bf8*)(wp + 16384 + 512);
#pragma unroll
    for (int ti = 0; ti < 3; ++ti) {
      const int rbase = (wv + ti * 4) * 16;
      f32x4 acc = MFMA_B16(Ax0[ti], Bn0, z);
      acc = MFMA_B16(Ax1[ti], Bn1, acc);
      acc = MFMA_B16(As0[ti], Bs0, acc);
      acc = MFMA_B16(As1[ti], Bs1, acc);
      acc = MFMA_B16(Ae0[ti], Be0, acc);
      acc = MFMA_B16(Ae1[ti], Be1, acc);
      const int j = ct * 16 + l15;
      const int c = j >> 1, h = j & 1;
#pragma unroll
      for (int r = 0; r < 4; ++r) {
        const int row = rbase + quad * 4 + r;
        eb16[row * 128 + ((c + row) & 63) * 2 + h] =
            (unsigned short)f2bf(acc[r]);
      }
    }
  }
  __syncthreads();

  const float inv = rsqrtf(1.f + EPSBN);
  const float s2 = g2[lane] * inv, o2 = b2[lane];
#pragma unroll
  for (int al = 0; al < 4; ++al) {
    const int a_local = wv * 4 + al;
    const int n = g * GAF + a_local;
    float acc = 0.f;
#pragma unroll
    for (int m = 0; m < 12; ++m) {
      const int row = a_local * 12 + m;
      const uint32_t eu = eb32[row * 64 + ((lane + row) & 63)];
      acc += sig(lo16(eu)) * sp(hi16(eu));
    }
    const size_t o = (size_t)n * 64 + lane;
    const float res = sp(xpre[al] + acc * s2 + o2);
    X[o] = res;
    const unsigned int u = (unsigned short)f2bf(res);
    const unsigned int p = __shfl_xor((int)u, 1);
    if (!(lane & 1)) XbOutU[(size_t)n * 32 + (lane >> 1)] = u | (p << 16);
  }
}

// ---------------------------------------------------------------------------
// FUSED conv layer, FALLBACK: verbatim R0 kernel (GA=8, proven 567 us).
// ---------------------------------------------------------------------------
__global__ __launch_bounds__(256, 5) void k_fused4(
    float* __restrict__ X, const unsigned short* __restrict__ XbIn,
    unsigned int* __restrict__ XbOutU, const float* __restrict__ NF,
    const int* __restrict__ IDX, const unsigned short* __restrict__ Wi,
    const float* __restrict__ g2, const float* __restrict__ b2) {
  __shared__ __align__(16) unsigned int eb32[ROWS * 64];  // 24576 B
  unsigned short* eb16 = (unsigned short*)eb32;
  float* stage = (float*)eb32;  // first 3936 floats = 96x41 tile
  const int tid = threadIdx.x;
  const int lane = tid & 63, wv = tid >> 6;
  const int quad = lane >> 4, l15 = lane & 15;
  const int g = blockIdx.x;
  const int ntile = (wv < 2) ? 2 : 1;  // 6 row-tiles over 4 waves

  bf8 Ax0[2], Ax1[2], As0[2], As1[2];
#pragma unroll
  for (int ti = 0; ti < 2; ++ti) {
    if (ti < ntile) {
      const int rbase = (wv + ti * 4) * 16;
      const int jr = IDX[g * ROWS + rbase + l15];
      const unsigned short* xr = XbIn + (size_t)jr * 64 + quad * 8;
      Ax0[ti] = *(const bf8*)xr;
      Ax1[ti] = *(const bf8*)(xr + 32);
      const int arow = g * GA + (rbase + l15) / M_NBR;
      const unsigned short* sr = XbIn + (size_t)arow * 64 + quad * 8;
      As0[ti] = *(const bf8*)sr;
      As1[ti] = *(const bf8*)(sr + 32);
    }
  }

  const float4* s4 = (const float4*)(NF + (size_t)g * (ROWS * NBF));
#pragma unroll
  for (int it = 0; it < 4; ++it) {
    const int w = tid + it * 256;
    if (w < (ROWS * NBF) / 4) ((float4*)stage)[w] = s4[w];
  }
  __syncthreads();

  bf8 Ae0[2], Ae1[2];
#pragma unroll
  for (int ti = 0; ti < 2; ++ti) {
    if (ti < ntile) {
      const int rbase = (wv + ti * 4) * 16;
      const float* rp = stage + (rbase + l15) * NBF;
      bf8 a0, a1;
#pragma unroll
      for (int i = 0; i < 8; ++i) a0[i] = f2bf(rp[quad * 8 + i]);
      if (quad == 0) {
#pragma unroll
        for (int i = 0; i < 8; ++i) a1[i] = f2bf(rp[32 + i]);
      } else if (quad == 1) {
        a1[0] = f2bf(rp[40]);
        a1[1] = (short)0x3F80;  // bf16 1.0 at k=41 -> multiplies bias row
#pragma unroll
        for (int i = 2; i < 8; ++i) a1[i] = 0;
      } else {
#pragma unroll
        for (int i = 0; i < 8; ++i) a1[i] = 0;
      }
      Ae0[ti] = a0;
      Ae1[ti] = a1;
    }
  }
  __syncthreads();

#pragma unroll
  for (int ti = 0; ti < 2; ++ti) {
    if (ti < ntile) {
      const int rbase = (wv + ti * 4) * 16;
      const f32x4 z = {0.f, 0.f, 0.f, 0.f};
#pragma unroll 1
      for (int ct = 0; ct < 8; ++ct) {
        const bf8 Be0 = *(const bf8*)(Wi + ((ct * 2 + 0) * 64 + lane) * 8);
        const bf8 Be1 = *(const bf8*)(Wi + ((ct * 2 + 1) * 64 + lane) * 8);
        const bf8 Bs0 =
            *(const bf8*)(Wi + 8192 + ((ct * 2 + 0) * 64 + lane) * 8);
        const bf8 Bs1 =
            *(const bf8*)(Wi + 8192 + ((ct * 2 + 1) * 64 + lane) * 8);
        const bf8 Bn0 =
            *(const bf8*)(Wi + 16384 + ((ct * 2 + 0) * 64 + lane) * 8);
        const bf8 Bn1 =
            *(const bf8*)(Wi + 16384 + ((ct * 2 + 1) * 64 + lane) * 8);
        f32x4 acc = MFMA_B16(Ax0[ti], Bn0, z);
        acc = MFMA_B16(Ax1[ti], Bn1, acc);
        acc = MFMA_B16(As0[ti], Bs0, acc);
        acc = MFMA_B16(As1[ti], Bs1, acc);
        acc = MFMA_B16(Ae0[ti], Be0, acc);
        acc = MFMA_B16(Ae1[ti], Be1, acc);
        const int j = ct * 16 + l15;
        const int c = j >> 1, h = j & 1;
#pragma unroll
        for (int r = 0; r < 4; ++r) {
          const int row = rbase + quad * 4 + r;
          eb16[row * 128 + ((c + row) & 63) * 2 + h] =
              (unsigned short)f2bf(acc[r]);
        }
      }
    }
  }
  __syncthreads();

  const float inv = rsqrtf(1.f + EPSBN);
  const float s2 = g2[lane] * inv, o2 = b2[lane];
#pragma unroll
  for (int al = 0; al < 2; ++al) {
    const int a_local = wv * 2 + al;
    const int n = g * GA + a_local;
    float acc = 0.f;
#pragma unroll
    for (int m = 0; m < 12; ++m) {
      const int row = a_local * 12 + m;
      const uint32_t eu = eb32[row * 64 + ((lane + row) & 63)];
      acc += sig(lo16(eu)) * sp(hi16(eu));
    }
    const size_t o = (size_t)n * 64 + lane;
    const float res = sp(X[o] + acc * s2 + o2);
    X[o] = res;
    const unsigned int u = (unsigned short)f2bf(res);
    const unsigned int p = __shfl_xor((int)u, 1);
    if (!(lane & 1)) XbOutU[(size_t)n * 32 + (lane >> 1)] = u | (p << 16);
  }
}

// ---------------------------------------------------------------------------
// Head: pooling with precomputed bounds, 256 threads (verbatim R8).
// ---------------------------------------------------------------------------
__global__ __launch_bounds__(256) void k_head(
    const float* __restrict__ Xf, const int* __restrict__ bounds,
    const float* __restrict__ EF, const float* __restrict__ Wx,
    const float* __restrict__ bx, const float* __restrict__ gx,
    const float* __restrict__ bxb, const float* __restrict__ Wfc,
    const float* __restrict__ bfc, const float* __restrict__ Wo0,
    const float* __restrict__ bo0, const float* __restrict__ Wo1,
    const float* __restrict__ bo1, const float* __restrict__ Wo2,
    const float* __restrict__ bo2, float* __restrict__ out) {
  const int b = blockIdx.x;
  const int t = threadIdx.x;
  __shared__ float vbuf[80];
  __shared__ float part[256];
  __shared__ float4 r4[128];
  const int lo = bounds[b];
  const int hi = bounds[b + 1];
  const int col = t & 63, qq = t >> 6;  // 4-way over rows
  float s = 0.f;
  for (int r = lo + qq; r < hi; r += 4) s += Xf[(size_t)r * 64 + col];
  part[t] = s;
  __syncthreads();
  if (t < 64) {
    vbuf[t] = (part[t] + part[t + 64] + part[t + 128] + part[t + 192]) /
              fmaxf((float)(hi - lo), 1.f);
  } else if (t < 80) {
    const int e = t - 64;
    float a = bx[e];
#pragma unroll
    for (int k = 0; k < 8; ++k) a += EF[b * 8 + k] * Wx[k * 16 + e];
    a = a * (gx[e] * rsqrtf(1.f + EPSBN)) + bxb[e];
    vbuf[t] = sp(a);
  }
  __syncthreads();
  if (t < 128) {
    float h = bfc[t];
#pragma unroll
    for (int k = 0; k < 80; ++k) h += vbuf[k] * Wfc[k * 128 + t];
    h = sp(h);
    r4[t] = make_float4(h * Wo0[t], h * Wo1[2 * t], h * Wo1[2 * t + 1],
                        h * Wo2[t]);
  }
  __syncthreads();
  for (int st2 = 64; st2 > 0; st2 >>= 1) {
    if (t < st2) {
      float4 a = r4[t], c = r4[t + st2];
      r4[t] = make_float4(a.x + c.x, a.y + c.y, a.z + c.z, a.w + c.w);
    }
    __syncthreads();
  }
  if (t == 0) {
    float4 r = r4[0];
    out[b] = r.x + bo0[0];
    float z0 = r.y + bo1[0], z1 = r.z + bo1[1];
    float mx = fmaxf(z0, z1);
    float lse = mx + __logf(__expf(z0 - mx) + __expf(z1 - mx));
    out[B_CRYS + 2 * b] = z0 - lse;
    out[B_CRYS + 2 * b + 1] = z1 - lse;
    out[3 * B_CRYS + b] = r.w + bo2[0];
  }
}

// ---------------------------------------------------------------------------
extern "C" void kernel_launch(void* const* d_in, const int* in_sizes, int n_in,
                              void* d_out, int out_size, void* d_ws,
                              size_t ws_size, hipStream_t stream) {
  const float* atom_fea = (const float*)d_in[0];
  const float* nbr_fea  = (const float*)d_in[1];
  const int*   nbr_idx  = (const int*)d_in[2];
  const int*   seg      = (const int*)d_in[3];
  const float* extra    = (const float*)d_in[4];
  const float* W_embed  = (const float*)d_in[5];
  const float* b_embed  = (const float*)d_in[6];
  const float* conv_W   = (const float*)d_in[7];
  const float* conv_b   = (const float*)d_in[8];
  const float* bn1_g    = (const float*)d_in[9];
  const float* bn1_b    = (const float*)d_in[10];
  const float* bn2_g    = (const float*)d_in[11];
  const float* bn2_b    = (const float*)d_in[12];
  const float* W_extra  = (const float*)d_in[13];
  const float* b_extra  = (const float*)d_in[14];
  const float* bnx_g    = (const float*)d_in[15];
  const float* bnx_b    = (const float*)d_in[16];
  const float* W_fc     = (const float*)d_in[17];
  const float* b_fc     = (const float*)d_in[18];
  const float* W_out0   = (const float*)d_in[19];
  const float* b_out0   = (const float*)d_in[20];
  const float* W_out1   = (const float*)d_in[21];
  const float* b_out1   = (const float*)d_in[22];
  const float* W_out2   = (const float*)d_in[23];
  const float* b_out2   = (const float*)d_in[24];
  float* out = (float*)d_out;

  // ws layout: X f32 | XbU0 | XbU1 | Wimg | bounds | [Eimg if it fits]
  float* x = (float*)d_ws;
  unsigned int* xbu0 = (unsigned int*)(x + (size_t)N_ATOMS * 64);
  unsigned int* xbu1 = xbu0 + (size_t)N_ATOMS * 32;
  unsigned short* Wimg = (unsigned short*)(xbu1 + (size_t)N_ATOMS * 32);
  int* bounds = (int*)(Wimg + (size_t)3 * WIMG_L);
  unsigned short* Eimg = (unsigned short*)(bounds + 2052);  // 16B-aligned

  const size_t base_bytes =
      (size_t)N_ATOMS * 64 * 4 + (size_t)N_ATOMS * 32 * 4 * 2 +
      (size_t)3 * WIMG_L * 2 + 2052 * 4;
  const size_t eimg_bytes = (size_t)EP_ROWS * EROW * 2;  // 69.12 MB
  const bool use_eimg = (ws_size >= base_bytes + eimg_bytes);

  hipLaunchKernelGGL(k_pre, dim3(PRE_GRID), dim3(256), 0, stream, conv_W,
                     conv_b, bn1_g, bn1_b, Wimg, atom_fea, W_embed, b_embed, x,
                     xbu0, seg, bounds);

  unsigned int* xin = xbu0;
  unsigned int* xout = xbu1;
  for (int i = 0; i < 3; ++i) {
    if (use_eimg) {
      if (i == 0) {
        hipLaunchKernelGGL(k_fused7, dim3(GRIDF), dim3(256), 0, stream, x,
                           (const unsigned short*)xin, xout, nbr_fea, Eimg,
                           nbr_idx, Wimg + (size_t)i * WIMG_L, bn2_g + i * 64,
                           bn2_b + i * 64);
      } else {
        hipLaunchKernelGGL(k_fused6, dim3(GRIDF), dim3(256), 0, stream, x,
                           (const unsigned short*)xin, xout, Eimg, nbr_idx,
                           Wimg + (size_t)i * WIMG_L, bn2_g + i * 64,
                           bn2_b + i * 64);
      }
    } else {
      hipLaunchKernelGGL(k_fused4, dim3(GRID_F), dim3(256), 0, stream, x,
                         (const unsigned short*)xin, xout, nbr_fea, nbr_idx,
                         Wimg + (size_t)i * WIMG_L, bn2_g + i * 64,
                         bn2_b + i * 64);
    }
    unsigned int* tmp = xin;
    xin = xout;
    xout = tmp;
  }
  hipLaunchKernelGGL(k_head, dim3(B_CRYS), dim3(256), 0, stream, x, bounds,
                     extra, W_extra, b_extra, bnx_g, bnx_b, W_fc, b_fc, W_out0,
                     b_out0, W_out1, b_out1, W_out2, b_out2, out);
}